// Round 1
// baseline (487.934 us; speedup 1.0000x reference)
//
#include <hip/hip_runtime.h>

// BilinearSampler: U[B,H,W,C] f32, grid[B,H,W,2] f32 -> out[B,H,W,C] f32
// B=16, H=256, W=256, C=64.
//
// v3: 4 threads per pixel (was 16), each thread owns 16 channels as 4x float4.
//  - 4x fewer waves; grid load + weight/addr math redundancy cut 16x -> 4x
//  - 16 independent U gathers per thread (vs 4) -> 4x memory-level parallelism
//  - 32-bit addressing (max float index 2^26 fits int) -> cheaper VALU addr calc
//  - keeps: NT store for the 256 MiB out stream, NT load for the 8 MiB grid
//    stream (preserve L2/L3 residency for U, which has 4x logical reuse),
//    64 B-contiguous per-pixel segments per load instruction (coalescing
//    sweet spot), 256 B-aligned corner reads.

#define BB 16
#define HH 256
#define WW 256
#define CC 64

typedef float vfloat4 __attribute__((ext_vector_type(4)));
typedef float vfloat2 __attribute__((ext_vector_type(2)));

__global__ __launch_bounds__(256) void
bilinear_kernel(const float* __restrict__ U,
                const float* __restrict__ grid,
                float* __restrict__ out) {
    const int tid   = blockIdx.x * 256 + threadIdx.x;
    const int pixel = tid >> 2;                // global pixel index in [0, B*H*W)
    const int c0    = (tid & 3) << 2;          // base channel 0/4/8/12; chunks add +16

    // grid coords: read-once stream -> non-temporal (don't pollute caches)
    const vfloat2 g = __builtin_nontemporal_load((const vfloat2*)grid + pixel);
    const float x = 0.5f * ((g.x + 1.0f) * (float)(WW - 1));
    const float y = 0.5f * ((g.y + 1.0f) * (float)(HH - 1));

    const float xf = floorf(x);
    const float yf = floorf(y);
    const int x0 = (int)xf;
    const int y0 = (int)yf;
    const int x1 = x0 + 1;
    const int y1 = y0 + 1;

    const int x0c = min(max(x0, 0), WW - 1);
    const int x1c = min(max(x1, 0), WW - 1);
    const int y0c = min(max(y0, 0), HH - 1);
    const int y1c = min(max(y1, 0), HH - 1);

    const float x0f = (float)x0c, x1f = (float)x1c;
    const float y0f = (float)y0c, y1f = (float)y1c;

    const float wa = (x1f - x) * (y1f - y);
    const float wb = (x1f - x) * (y - y0f);
    const float wc = (x - x0f) * (y1f - y);
    const float wd = (x - x0f) * (y - y0f);

    // 32-bit addressing: max index = 16*256*256*64 = 2^26 floats, fits int.
    const int b    = pixel >> 16;              // pixel / (H*W), H*W = 65536
    const int base = b * (HH * WW * CC) + c0;

    const float4* __restrict__ A =
        (const float4*)(U + base + (y0c * WW + x0c) * CC);
    const float4* __restrict__ Bp =
        (const float4*)(U + base + (y1c * WW + x0c) * CC);
    const float4* __restrict__ Cp =
        (const float4*)(U + base + (y0c * WW + x1c) * CC);
    const float4* __restrict__ D =
        (const float4*)(U + base + (y1c * WW + x1c) * CC);

    float* __restrict__ o = out + pixel * CC + c0;

    // 4 chunks of 4 channels; chunk i covers channels c0 + 16*i .. +3.
    // Fully unrolled: compiler can hoist all 16 independent gathers.
#pragma unroll
    for (int i = 0; i < 4; ++i) {
        const float4 Ia = A[i * 4];            // +16 floats per chunk
        const float4 Ib = Bp[i * 4];
        const float4 Ic = Cp[i * 4];
        const float4 Id = D[i * 4];

        vfloat4 r;
        r.x = wa * Ia.x + wb * Ib.x + wc * Ic.x + wd * Id.x;
        r.y = wa * Ia.y + wb * Ib.y + wc * Ic.y + wd * Id.y;
        r.z = wa * Ia.z + wb * Ib.z + wc * Ic.z + wd * Id.z;
        r.w = wa * Ia.w + wb * Ib.w + wc * Ic.w + wd * Id.w;

        // output: pure write stream -> non-temporal store
        __builtin_nontemporal_store(r, (vfloat4*)(o + i * 16));
    }
}

extern "C" void kernel_launch(void* const* d_in, const int* in_sizes, int n_in,
                              void* d_out, int out_size, void* d_ws, size_t ws_size,
                              hipStream_t stream) {
    const float* U    = (const float*)d_in[0];
    const float* grid = (const float*)d_in[1];
    float* out        = (float*)d_out;

    const int n_pixels  = BB * HH * WW;        // 1,048,576
    const int n_threads = n_pixels * 4;        // 4,194,304
    const int n_blocks  = n_threads / 256;     // 16,384

    bilinear_kernel<<<n_blocks, 256, 0, stream>>>(U, grid, out);
}